// Round 7
// baseline (612.646 us; speedup 1.0000x reference)
//
#include <hip/hip_runtime.h>

#define H 1024
#define E 64
#define BT 128          // tokens per block
#define NG 4            // in-block split-K groups
#define KG (H / NG)     // 256 K per group
#define BK 16           // k-chunk per stage
#define NCH (KG / BK)   // 16 chunks
#define PADF 20         // LDS row stride in floats (5 f4)
#define R 8             // tokens per thread
#define C 8             // experts per thread

typedef float __attribute__((ext_vector_type(4))) f4;

// Split-K 8x8-tile GEMM. 512 threads = 4 K-groups x 128 threads; group g
// computes the full 128x64 logit tile over K [256g, 256g+256) with an 8x8
// per-thread register tile; partials summed in LDS at the end.
// Why: round-0 (4x4 tile) was LDS-data-pipe bound: ratio 8 FMA/ds_read_b128
// -> 16K reads/CU x 12cyc = 82us (measured 100). 8x8 tile halves LDS reads
// (ratio 16 -> 41us), and split-K restores wave count (2048 waves, 8/CU)
// that plain 8x8 tiling would lose. W stays in LDS (VMEM-W = 196us r1,
// SMEM-W = 284us r3 -- both pipes proven worse).
// Bank math (stride PADF=20 dw): a-reads rows {ty+16r}, b-reads rows
// {tx+8c}; consecutive group index -> addr stride 20 dw; 8 distinct
// bank-starts {0,20,8,28,16,4,24,12} x 4-bank span = all 32 banks,
// 8-lane broadcast on each -> conflict-free.
__global__ __launch_bounds__(512, 2) void moe_gate_kernel(
    const float* __restrict__ x, const float* __restrict__ W,
    float* __restrict__ out, int T) {
  __shared__ __align__(16) float xs[NG][BT][PADF];  // 40960 B
  __shared__ __align__(16) float ws[NG][E][PADF];   // 20480 B  (61440 total)
  // epilogue logits tile overlays xs (dead after K loop): 128*65*4 = 33280 B
  float(*ls)[E + 1] = (float(*)[E + 1])xs;

  const int tid = threadIdx.x;
  const int g = __builtin_amdgcn_readfirstlane(tid >> 7);  // K-group 0..3
  const int tg = tid & 127;
  const int tx = tg & 7;         // experts tx + 8c
  const int ty = tg >> 3;        // tokens  ty + 16r
  const int t0 = blockIdx.x * BT;
  const int kbase = g * KG;

  float acc[R][C];
#pragma unroll
  for (int r = 0; r < R; ++r)
#pragma unroll
    for (int c = 0; c < C; ++c) acc[r][c] = 0.f;

  // staging maps: xs 4 f4/thread, ws 2 f4/thread (within the group's 128)
  int xrow[4], xcol[4], wrow[2], wcol[2];
#pragma unroll
  for (int k = 0; k < 4; ++k) {
    int id = tg + (k << 7);
    xrow[k] = id >> 2; xcol[k] = id & 3;
  }
#pragma unroll
  for (int k = 0; k < 2; ++k) {
    int id = tg + (k << 7);
    wrow[k] = id >> 2; wcol[k] = id & 3;
  }

  // prologue: stage chunk 0
#pragma unroll
  for (int k = 0; k < 4; ++k)
    *(f4*)&xs[g][xrow[k]][xcol[k] << 2] =
        *(const f4*)&x[(size_t)(t0 + xrow[k]) * H + kbase + (xcol[k] << 2)];
#pragma unroll
  for (int k = 0; k < 2; ++k)
    *(f4*)&ws[g][wrow[k]][wcol[k] << 2] =
        *(const f4*)&W[(size_t)wrow[k] * H + kbase + (wcol[k] << 2)];
  __syncthreads();

  for (int ch = 0; ch < NCH; ++ch) {
    const bool more = ch + 1 < NCH;
    // register-prefetch next chunk (VMEM latency hides under 1024 FMAs)
    f4 px[4], pw[2];
    if (more) {
      const int ko = kbase + (ch + 1) * BK;
#pragma unroll
      for (int k = 0; k < 4; ++k)
        px[k] = *(const f4*)&x[(size_t)(t0 + xrow[k]) * H + ko + (xcol[k] << 2)];
#pragma unroll
      for (int k = 0; k < 2; ++k)
        pw[k] = *(const f4*)&W[(size_t)wrow[k] * H + ko + (wcol[k] << 2)];
    }

#pragma unroll
    for (int j = 0; j < BK / 4; ++j) {
      f4 a[R], b[C];
#pragma unroll
      for (int r = 0; r < R; ++r)
        a[r] = *(const f4*)&xs[g][ty + (r << 4)][j << 2];
#pragma unroll
      for (int c = 0; c < C; ++c)
        b[c] = *(const f4*)&ws[g][tx + (c << 3)][j << 2];
#pragma unroll
      for (int r = 0; r < R; ++r)
#pragma unroll
        for (int c = 0; c < C; ++c) {
          acc[r][c] = fmaf(a[r].x, b[c].x, acc[r][c]);
          acc[r][c] = fmaf(a[r].y, b[c].y, acc[r][c]);
          acc[r][c] = fmaf(a[r].z, b[c].z, acc[r][c]);
          acc[r][c] = fmaf(a[r].w, b[c].w, acc[r][c]);
        }
    }
    __syncthreads();   // all reads of chunk ch done
    if (more) {
#pragma unroll
      for (int k = 0; k < 4; ++k)
        *(f4*)&xs[g][xrow[k]][xcol[k] << 2] = px[k];
#pragma unroll
      for (int k = 0; k < 2; ++k)
        *(f4*)&ws[g][wrow[k]][wcol[k] << 2] = pw[k];
    }
    __syncthreads();   // chunk ch+1 visible
  }

  // split-K reduction in LDS: group 0 writes, groups 1..3 add.
  if (g == 0) {
#pragma unroll
    for (int r = 0; r < R; ++r)
#pragma unroll
      for (int c = 0; c < C; ++c)
        ls[ty + (r << 4)][tx + (c << 3)] = acc[r][c];
  }
  __syncthreads();
  if (g != 0) {
#pragma unroll
    for (int r = 0; r < R; ++r)
#pragma unroll
      for (int c = 0; c < C; ++c)
        atomicAdd(&ls[ty + (r << 4)][tx + (c << 3)], acc[r][c]);
  }
  __syncthreads();

  // per-token epilogue: 128 lanes, one per token (ls stride 65: conflict-free).
  // top-2 of logits == top-2 of softmax (monotonic); tie-break lower index
  // first (matches jax.lax.top_k).
  if (tid < BT) {
    const int tk = tid;
    float m1 = -1e30f, m2 = -1e30f;
    int i1 = 0, i2 = 0;
#pragma unroll
    for (int e = 0; e < E; ++e) {
      float v = ls[tk][e];
      if (v > m1) {
        m2 = m1; i2 = i1;
        m1 = v;  i1 = e;
      } else if (v > m2) {
        m2 = v; i2 = e;
      }
    }
    float s = 0.f;
#pragma unroll
    for (int e = 0; e < E; ++e) s += expf(ls[tk][e] - m1);
    float p1 = 1.f / s;                 // exp(m1-m1)/s
    float p2 = expf(m2 - m1) / s;
    // second softmax over [p1, p2] (p1 >= p2 so exponent <= 0: stable)
    float e12 = expf(p2 - p1);
    float s1 = 1.f / (1.f + e12);
    float s2 = e12 * s1;

    size_t t = (size_t)(t0 + tk);
    out[t * 2 + 0] = s1;
    out[t * 2 + 1] = s2;
    float* idxo = out + (size_t)2 * T;
    idxo[t * 2 + 0] = (float)i1;
    idxo[t * 2 + 1] = (float)i2;
  }

  // trailing scalar output: zeros(())
  if (blockIdx.x == 0 && tid == 0) out[(size_t)4 * T] = 0.f;
}

extern "C" void kernel_launch(void* const* d_in, const int* in_sizes, int n_in,
                              void* d_out, int out_size, void* d_ws, size_t ws_size,
                              hipStream_t stream) {
  const float* x = (const float*)d_in[0];
  const float* W = (const float*)d_in[1];
  float* out = (float*)d_out;
  const int T = in_sizes[0] / H;  // 4*8192 = 32768 tokens
  dim3 grid(T / BT), block(512);
  hipLaunchKernelGGL(moe_gate_kernel, grid, block, 0, stream, x, W, out, T);
}

// Round 8
// 265.680 us; speedup vs baseline: 2.3060x; 2.3060x over previous
//
#include <hip/hip_runtime.h>

#define H 1024
#define E 64
#define BT 128          // tokens per block
#define NG 4            // in-block split-K groups
#define KG (H / NG)     // 256 K per group
#define BK 16           // k-chunk per stage
#define NCH (KG / BK)   // 16 chunks
#define R 8             // tokens per thread
#define C 8             // experts per thread

typedef float __attribute__((ext_vector_type(4))) f4;
typedef __attribute__((address_space(1))) const void gvoid;  // global
typedef __attribute__((address_space(3))) void svoid;        // LDS

// Split-K 8x8-tile GEMM, register-lean. 512 threads = 4 K-groups x 128.
// Round-7 failed on VGPR spill (WRITE_SIZE 1GB of scratch): acc64+a8+b8+
// prefetch24 ~ 176 regs > 128 cap. Fixes: (1) stream b (peak ~120 regs);
// (2) staging via global_load_lds width=16 -- zero staging registers,
// DMA drained by __syncthreads' vmcnt(0). DMA needs a LINEAR LDS dest
// (no padding), so bank conflicts are fixed by XOR swizzle instead:
// phys f4col = logical ^ (row&3), applied by pre-swizzling the per-lane
// GLOBAL source address (DMA dest stays linear) and by the same XOR on
// ds_read. a-reads (rows ty+16r) and b-reads (rows tx+8c): ty/tx and
// ty/tx+4 land on the same bank-group with different addresses -> 2-way
// aliasing = free (m136). Ratio 16 FMA per ds_read_b128 -> LDS pipe
// ~41us, VALU 27us: LDS-bound ~45us target.
__global__ __launch_bounds__(512, 2) void moe_gate_kernel(
    const float* __restrict__ x, const float* __restrict__ W,
    float* __restrict__ out, int T) {
  __shared__ __align__(16) float xs[2][NG][BT][BK];  // 65536 B
  __shared__ __align__(16) float ws[2][NG][E][BK];   // 32768 B (98304 total)
  // epilogue logits tile overlays xs (dead after K loop): 128*65*4 = 33280 B
  float(*ls)[E + 1] = (float(*)[E + 1])xs;

  const int tid = threadIdx.x;
  const int lane = tid & 63;
  const int wid = tid >> 6;      // 0..7
  const int g = wid >> 1;        // K-group 0..3
  const int w = wid & 1;         // wave within group
  const int tg = tid & 127;
  const int tx = tg & 7;         // experts tx + 8c
  const int ty = tg >> 3;        // tokens  ty + 16r  (0..15)
  const int t0 = blockIdx.x * BT;
  const int kbase = g * KG;

  const int lr = lane >> 2;      // lane's row within a 16-row slab
  const int lc = lane & 3;       // lane's phys f4 col (DMA writes lane*16B)

  // DMA one chunk of this group's x (128 rows) and W (64 rows) into buf.
  // Each wave covers 16 rows (64 lanes x 16B = 1KB contiguous) per issue;
  // global source pre-swizzled so phys col lc holds logical col lc^(row&3).
  auto stage = [&](int buf, int ch) {
    const int ko = kbase + ch * BK;
#pragma unroll
    for (int m = 0; m < 4; ++m) {
      const int row0 = 16 * w + 32 * m;          // uniform per wave
      const int r = row0 + lr;
      const int c4 = lc ^ (r & 3);
      __builtin_amdgcn_global_load_lds(
          (gvoid*)(x + (size_t)(t0 + r) * H + ko + 4 * c4),
          (svoid*)&xs[buf][g][row0][0], 16, 0, 0);
    }
#pragma unroll
    for (int m = 0; m < 2; ++m) {
      const int row0 = 16 * w + 32 * m;          // rows 0..63 over w,m
      const int r = row0 + lr;
      const int c4 = lc ^ (r & 3);
      __builtin_amdgcn_global_load_lds(
          (gvoid*)(W + (size_t)r * H + ko + 4 * c4),
          (svoid*)&ws[buf][g][row0][0], 16, 0, 0);
    }
  };

  float acc[R][C];
#pragma unroll
  for (int r = 0; r < R; ++r)
#pragma unroll
    for (int c = 0; c < C; ++c) acc[r][c] = 0.f;

  stage(0, 0);
  __syncthreads();   // implicit s_waitcnt vmcnt(0) before s_barrier

  const int xa = ty & 3, xb = tx & 3;
  int buf = 0;
  for (int ch = 0; ch < NCH; ++ch) {
    if (ch + 1 < NCH) stage(buf ^ 1, ch + 1);  // async DMA under compute
#pragma unroll
    for (int j = 0; j < BK / 4; ++j) {
      f4 a[R];
#pragma unroll
      for (int r = 0; r < R; ++r)
        a[r] = *(const f4*)&xs[buf][g][ty + 16 * r][4 * (j ^ xa)];
#pragma unroll
      for (int c = 0; c < C; ++c) {
        const f4 b = *(const f4*)&ws[buf][g][tx + 8 * c][4 * (j ^ xb)];
#pragma unroll
        for (int r = 0; r < R; ++r) {
          acc[r][c] = fmaf(a[r].x, b.x, acc[r][c]);
          acc[r][c] = fmaf(a[r].y, b.y, acc[r][c]);
          acc[r][c] = fmaf(a[r].z, b.z, acc[r][c]);
          acc[r][c] = fmaf(a[r].w, b.w, acc[r][c]);
        }
      }
    }
    __syncthreads();  // drains my DMA (vmcnt 0) + all waves' reads of buf
    buf ^= 1;
  }

  // split-K reduction in LDS: group 0 writes, groups 1..3 add.
  if (g == 0) {
#pragma unroll
    for (int r = 0; r < R; ++r)
#pragma unroll
      for (int c = 0; c < C; ++c)
        ls[ty + (r << 4)][tx + (c << 3)] = acc[r][c];
  }
  __syncthreads();
  if (g != 0) {
#pragma unroll
    for (int r = 0; r < R; ++r)
#pragma unroll
      for (int c = 0; c < C; ++c)
        atomicAdd(&ls[ty + (r << 4)][tx + (c << 3)], acc[r][c]);
  }
  __syncthreads();

  // per-token epilogue: 128 lanes, one per token (ls stride 65: 2-way max).
  // top-2 of logits == top-2 of softmax (monotonic); tie-break lower index
  // first (matches jax.lax.top_k).
  if (tid < BT) {
    const int tk = tid;
    float m1 = -1e30f, m2 = -1e30f;
    int i1 = 0, i2 = 0;
#pragma unroll
    for (int e = 0; e < E; ++e) {
      float v = ls[tk][e];
      if (v > m1) {
        m2 = m1; i2 = i1;
        m1 = v;  i1 = e;
      } else if (v > m2) {
        m2 = v; i2 = e;
      }
    }
    float s = 0.f;
#pragma unroll
    for (int e = 0; e < E; ++e) s += expf(ls[tk][e] - m1);
    float p1 = 1.f / s;                 // exp(m1-m1)/s
    float p2 = expf(m2 - m1) / s;
    // second softmax over [p1, p2] (p1 >= p2 so exponent <= 0: stable)
    float e12 = expf(p2 - p1);
    float s1 = 1.f / (1.f + e12);
    float s2 = e12 * s1;

    size_t t = (size_t)(t0 + tk);
    out[t * 2 + 0] = s1;
    out[t * 2 + 1] = s2;
    float* idxo = out + (size_t)2 * T;
    idxo[t * 2 + 0] = (float)i1;
    idxo[t * 2 + 1] = (float)i2;
  }

  // trailing scalar output: zeros(())
  if (blockIdx.x == 0 && tid == 0) out[(size_t)4 * T] = 0.f;
}

extern "C" void kernel_launch(void* const* d_in, const int* in_sizes, int n_in,
                              void* d_out, int out_size, void* d_ws, size_t ws_size,
                              hipStream_t stream) {
  const float* x = (const float*)d_in[0];
  const float* W = (const float*)d_in[1];
  float* out = (float*)d_out;
  const int T = in_sizes[0] / H;  // 4*8192 = 32768 tokens
  dim3 grid(T / BT), block(512);
  hipLaunchKernelGGL(moe_gate_kernel, grid, block, 0, stream, x, W, out, T);
}